// Round 3
// baseline (6178.984 us; speedup 1.0000x reference)
//
#include <hip/hip_runtime.h>
#include <hip/hip_bf16.h>

#define B 64
#define T 8192
#define D 16
#define H 128
#define F 17          // D + 1 features
#define NTHREADS 512
#define MB 16         // batches per block
#define NBLK 4        // B / MB
#define LSTR 168      // LDS row stride (halfs); fits k<160, bank-friendly
#define GI_T (NBLK * 128 * 48)   // halfs per timestep in gi workspace

typedef _Float16 half_t;
typedef _Float16 f16x8 __attribute__((ext_vector_type(8)));
typedef _Float16 f16x4 __attribute__((ext_vector_type(4)));
typedef float f32x4 __attribute__((ext_vector_type(4)));

#define MFMA(a, b, c) __builtin_amdgcn_mfma_f32_16x16x32_f16((a), (b), (c), 0, 0, 0)

__device__ __forceinline__ float fast_rcp(float x) {
#if __has_builtin(__builtin_amdgcn_rcpf)
  return __builtin_amdgcn_rcpf(x);
#else
  return 1.0f / x;
#endif
}

struct GiR { f16x4 r, z, n; };

// A-fragment read: lane = row m = (l&15); k = s*32 + (l>>4)*8 + i  (contig 16B)
#define AFRAG(hp, s) (*(const f16x8*)((hp) + arow * LSTR + (s) * 32 + mg * 8))

// ---------------- gi precompute: gi[t][g][j][gate][m] = (x[g*16+m,t,:] @ Wi)[gate*128+j]
__global__ __launch_bounds__(NTHREADS)
void gi_kernel(const float* __restrict__ particles, const float* __restrict__ weights,
               const float* __restrict__ Wi, half_t* __restrict__ gi)
{
  __shared__ float xs[MB][32][F];     // 34.8 KB
  __shared__ float wis[F][384];       // 26.1 KB
  const int g  = blockIdx.x & 3;
  const int t0 = (blockIdx.x >> 2) * 32;
  const int tid = threadIdx.x;

  for (int i = tid; i < F * 384; i += NTHREADS) wis[i / 384][i % 384] = Wi[i];
  for (int i = tid; i < MB * 32 * F; i += NTHREADS) {
    int m = i / (32 * F), rest = i % (32 * F), t = rest / F, f = rest % F;
    xs[m][t][f] = (f < D) ? particles[((size_t)(g * MB + m) * T + t0 + t) * D + f]
                          : weights[(size_t)(g * MB + m) * T + t0 + t];
  }
  __syncthreads();

  #pragma unroll 1
  for (int k = 0; k < 12; ++k) {
    const int e = tid + NTHREADS * k;       // 6144 entries: j*48 + gate*16 + m
    const int j = e / 48, r2 = e % 48, gate = r2 >> 4, m = r2 & 15;
    const int col = gate * 128 + j;
    #pragma unroll 1
    for (int t = 0; t < 32; ++t) {
      float s = 0.f;
      #pragma unroll
      for (int f = 0; f < F; ++f) s = fmaf(xs[m][t][f], wis[f][col], s);
      gi[(size_t)(t0 + t) * GI_T + g * 6144 + e] = (half_t)s;
    }
  }
}

// ---------------- GRU scan + MLP. GIP: gi precomputed in global; else fused K=160.
template<bool GIP>
__global__ __launch_bounds__(NTHREADS)
void policy_gru_kernel(const float* __restrict__ particles,
                       const float* __restrict__ weights,
                       const float* __restrict__ Wi, const float* __restrict__ Wh,
                       const float* __restrict__ bh,
                       const float* __restrict__ W1, const float* __restrict__ b1,
                       const float* __restrict__ W2, const float* __restrict__ b2,
                       const float* __restrict__ W3, const float* __restrict__ b3,
                       const float* __restrict__ log_std,
                       const half_t* __restrict__ gi,
                       float* __restrict__ out)
{
  __shared__ __align__(16) half_t hbuf[2][MB * LSTR];  // [m][k], k: h(128)|x(17)|pad
  __shared__ float sgH[MB * H];
  __shared__ float sgA[MB * 256];

  const int tid = threadIdx.x;
  const int b0  = blockIdx.x * MB;
  const int l   = tid & 63;
  const int w   = tid >> 6;        // wave 0..7 owns j-chunk w
  const int mg  = l >> 4;          // k-group for A; batch-group for D
  const int jn  = l & 15;
  const int arow = jn;             // A row (batch) this lane reads
  const int jcol = w * 16 + jn;    // gate col (hidden unit) this lane computes
  const int m0   = mg * 4;         // first of this lane's 4 D-rows (batches)

  // ---- B-fragments (persistent): B[k][n]: n = gbase+jcol, k = s*32 + mg*8 + r
  auto wload = [&](int gate, int s) -> f16x8 {
    f16x8 v;
    #pragma unroll
    for (int r = 0; r < 8; ++r) {
      const int k = s * 32 + mg * 8 + r;
      const int col = (gate == 0) ? jcol : (gate == 1) ? 128 + jcol : 256 + jcol;
      float f = 0.0f;
      if (gate <= 1) {
        if (k < 128) f = Wh[k * 384 + col];
        else if (k < 128 + F) f = Wi[(k - 128) * 384 + col];
      } else if (gate == 2) {
        if (k < 128) f = Wh[k * 384 + col];
      } else {
        if (k >= 128 && k < 128 + F) f = Wi[(k - 128) * 384 + col];
      }
      v[r] = (half_t)f;
    }
    return v;
  };
  const f16x8 wr0 = wload(0,0), wr1 = wload(0,1), wr2 = wload(0,2), wr3 = wload(0,3);
  const f16x8 wz0 = wload(1,0), wz1 = wload(1,1), wz2 = wload(1,2), wz3 = wload(1,3);
  const f16x8 wn0 = wload(2,0), wn1 = wload(2,1), wn2 = wload(2,2), wn3 = wload(2,3);
  f16x8 wr4 = {}, wz4 = {}, wi4 = {};
  if (!GIP) { wr4 = wload(0,4); wz4 = wload(1,4); wi4 = wload(3,4); }
  const float b_r = bh[jcol], b_z = bh[128 + jcol], b_n = bh[256 + jcol];

  // ---- fused-path x stagers: threads 0..271 own (xm, xf)
  const bool isx = !GIP && (tid < MB * F);
  const int xm = isx ? tid / F : 0, xf = isx ? tid % F : 0;
  auto xload = [&](int t) -> float {
    if (!isx) return 0.0f;
    if (xf < D) return particles[((size_t)(b0 + xm) * T + t) * D + xf];
    return weights[(size_t)(b0 + xm) * T + t];
  };

  // ---- gi prefetch base
  const half_t* gbase = GIP ? (gi + blockIdx.x * 6144 + jcol * 48 + 4 * mg) : nullptr;
  auto gload = [&](GiR& gu, int t) {
    const half_t* gp = gbase + (size_t)t * GI_T;
    gu.r = *(const f16x4*)(gp);
    gu.z = *(const f16x4*)(gp + 16);
    gu.n = *(const f16x4*)(gp + 32);
  };

  // ---- init
  for (int i = tid; i < 2 * MB * LSTR; i += NTHREADS)
    ((half_t*)hbuf)[i] = (half_t)0.f;
  float hreg[4] = {0.f, 0.f, 0.f, 0.f};   // h[m0+i][jcol]
  __syncthreads();
  float xA = 0, xB = 0, xC = 0, xD = 0;
  GiR g0 = {}, g1 = {}, g2 = {}, g3 = {};
  if (GIP) { gload(g0, 0); gload(g1, 1); gload(g2, 2); gload(g3, 3); }
  else {
    if (isx) hbuf[0][xm * LSTR + 128 + xf] = (half_t)xload(0);
    xA = xload(1); xB = xload(2); xC = xload(3); xD = xload(4);
  }
  __syncthreads();

#define GSTEP(RB, WB, GU, XV, TT)                                              \
  do {                                                                         \
    const half_t* hp = (RB);                                                   \
    f16x8 a0 = AFRAG(hp,0), a1 = AFRAG(hp,1), a2 = AFRAG(hp,2), a3 = AFRAG(hp,3);\
    f32x4 ar, az, an, ai;                                                      \
    if constexpr (GIP) {                                                       \
      _Pragma("unroll")                                                        \
      for (int i = 0; i < 4; ++i) {                                            \
        ar[i] = b_r + (float)GU.r[i]; az[i] = b_z + (float)GU.z[i];            \
        an[i] = b_n;                  ai[i] = (float)GU.n[i];                  \
      }                                                                        \
      gload(GU, (TT) + 4 < T ? (TT) + 4 : T - 1);                              \
      ar = MFMA(a0, wr0, ar); az = MFMA(a0, wz0, az); an = MFMA(a0, wn0, an);  \
      ar = MFMA(a1, wr1, ar); az = MFMA(a1, wz1, az); an = MFMA(a1, wn1, an);  \
      ar = MFMA(a2, wr2, ar); az = MFMA(a2, wz2, az); an = MFMA(a2, wn2, an);  \
      ar = MFMA(a3, wr3, ar); az = MFMA(a3, wz3, az); an = MFMA(a3, wn3, an);  \
    } else {                                                                   \
      f16x8 a4 = AFRAG(hp, 4);                                                 \
      _Pragma("unroll")                                                        \
      for (int i = 0; i < 4; ++i) { ar[i] = b_r; az[i] = b_z; an[i] = b_n; ai[i] = 0.f; } \
      ar = MFMA(a0, wr0, ar); az = MFMA(a0, wz0, az); an = MFMA(a0, wn0, an);  \
      ar = MFMA(a1, wr1, ar); az = MFMA(a1, wz1, az); an = MFMA(a1, wn1, an);  \
      ar = MFMA(a2, wr2, ar); az = MFMA(a2, wz2, az); an = MFMA(a2, wn2, an);  \
      ar = MFMA(a3, wr3, ar); az = MFMA(a3, wz3, az); an = MFMA(a3, wn3, an);  \
      ar = MFMA(a4, wr4, ar); az = MFMA(a4, wz4, az); ai = MFMA(a4, wi4, ai);  \
    }                                                                          \
    _Pragma("unroll")                                                          \
    for (int i = 0; i < 4; ++i) {                                              \
      float rr = fast_rcp(1.0f + __expf(-ar[i]));                              \
      float zz = fast_rcp(1.0f + __expf(-az[i]));                              \
      float pre = fmaf(rr, an[i], ai[i]);                                      \
      pre = fminf(fmaxf(pre, -15.0f), 15.0f);                                  \
      float e2 = __expf(-2.0f * pre);                                          \
      float nn = (1.0f - e2) * fast_rcp(1.0f + e2);                            \
      hreg[i] = fmaf(zz, hreg[i] - nn, nn);                                    \
      (WB)[(m0 + i) * LSTR + jcol] = (half_t)hreg[i];                          \
    }                                                                          \
    if constexpr (!GIP) {                                                      \
      if (isx) (WB)[xm * LSTR + 128 + xf] = (half_t)(XV);                      \
      XV = xload((TT) + 5 < T ? (TT) + 5 : T - 1);                             \
    }                                                                          \
    __syncthreads();                                                           \
  } while (0)

  for (int t = 0; t < T; t += 4) {
    GSTEP(hbuf[0], hbuf[1], g0, xA, t);
    GSTEP(hbuf[1], hbuf[0], g1, xB, t + 1);
    GSTEP(hbuf[0], hbuf[1], g2, xC, t + 2);
    GSTEP(hbuf[1], hbuf[0], g3, xD, t + 3);
  }
#undef GSTEP

  // ---- MLP head (fp32), 16 batches per block
  #pragma unroll
  for (int i = 0; i < 4; ++i) sgH[(m0 + i) * H + jcol] = hreg[i];
  __syncthreads();

  const int mm = tid >> 5;          // batch 0..15
  const int u0 = (tid & 31) * 8;    // 8 units per thread
  float a1v[8];
  #pragma unroll
  for (int u = 0; u < 8; ++u) a1v[u] = b1[u0 + u];
  #pragma unroll 1
  for (int k = 0; k < H; ++k) {
    const float hv = sgH[mm * H + k];
    #pragma unroll
    for (int u = 0; u < 8; ++u) a1v[u] = fmaf(hv, W1[k * 256 + u0 + u], a1v[u]);
  }
  #pragma unroll
  for (int u = 0; u < 8; ++u) sgA[mm * 256 + u0 + u] = fmaxf(a1v[u], 0.f);
  __syncthreads();

  float p = 0.f;
  #pragma unroll 1
  for (int u = 0; u < 8; ++u) {
    float a2v = b2[u0 + u];
    #pragma unroll 4
    for (int k = 0; k < 256; ++k) a2v = fmaf(sgA[mm * 256 + k], W2[k * 256 + u0 + u], a2v);
    p = fmaf(fmaxf(a2v, 0.f), W3[u0 + u], p);
  }
  #pragma unroll
  for (int off = 16; off > 0; off >>= 1) p += __shfl_down(p, off, 32);
  if ((tid & 31) == 0) out[b0 + mm] = p + b3[0];
  if (blockIdx.x == 0 && tid == 0) out[B] = log_std[0];
}

extern "C" void kernel_launch(void* const* d_in, const int* in_sizes, int n_in,
                              void* d_out, int out_size, void* d_ws, size_t ws_size,
                              hipStream_t stream) {
  const float* particles = (const float*)d_in[0];
  const float* weights   = (const float*)d_in[1];
  const float* Wi      = (const float*)d_in[2];
  const float* Wh      = (const float*)d_in[3];
  const float* bh      = (const float*)d_in[4];
  const float* W1      = (const float*)d_in[5];
  const float* b1      = (const float*)d_in[6];
  const float* W2      = (const float*)d_in[7];
  const float* b2      = (const float*)d_in[8];
  const float* W3      = (const float*)d_in[9];
  const float* b3      = (const float*)d_in[10];
  const float* log_std = (const float*)d_in[11];

  const size_t gi_bytes = (size_t)T * GI_T * sizeof(half_t);  // ~384 MiB
  if (ws_size >= gi_bytes) {
    half_t* gi = (half_t*)d_ws;
    gi_kernel<<<dim3(NBLK * (T / 32)), dim3(NTHREADS), 0, stream>>>(
        particles, weights, Wi, gi);
    policy_gru_kernel<true><<<dim3(NBLK), dim3(NTHREADS), 0, stream>>>(
        particles, weights, Wi, Wh, bh, W1, b1, W2, b2, W3, b3, log_std,
        gi, (float*)d_out);
  } else {
    policy_gru_kernel<false><<<dim3(NBLK), dim3(NTHREADS), 0, stream>>>(
        particles, weights, Wi, Wh, bh, W1, b1, W2, b2, W3, b3, log_std,
        nullptr, (float*)d_out);
  }
}

// Round 4
// 5479.062 us; speedup vs baseline: 1.1277x; 1.1277x over previous
//
#include <hip/hip_runtime.h>
#include <hip/hip_bf16.h>

#define B 64
#define T 8192
#define D 16
#define H 128
#define F 17        // D + 1 features
#define NTHREADS 512

typedef _Float16 half_t;
typedef _Float16 f16x8 __attribute__((ext_vector_type(8)));
typedef float f32x4 __attribute__((ext_vector_type(4)));

#define MFMA(a, b, c) __builtin_amdgcn_mfma_f32_16x16x32_f16((a), (b), (c), 0, 0, 0)

__device__ __forceinline__ float fast_rcp(float x) {
#if __has_builtin(__builtin_amdgcn_rcpf)
  return __builtin_amdgcn_rcpf(x);
#else
  return 1.0f / x;
#endif
}
__device__ __forceinline__ float fast_exp2(float x) {
#if __has_builtin(__builtin_amdgcn_exp2f)
  return __builtin_amdgcn_exp2f(x);
#else
  return exp2f(x);
#endif
}

struct XT { float v[F]; };   // one timestep's input row (uniform per block)
struct GI { float r, z, n; };

// One GRU step. RB holds h_t (128 f16). GE holds this step's gi (x-part,
// biases folded, prescaled). XV holds x_{tt+2}; we consume it to rebuild GE
// for step tt+2 and then prefetch x_{tt+4} into it. One barrier per step.
#define GSTEP(RB, WB, GE, XV, TT)                                            \
  do {                                                                       \
    const f16x8* hv = (const f16x8*)(RB);                                    \
    f16x8 a0 = hv[mg], a1 = hv[4 + mg], a2 = hv[8 + mg], a3 = hv[12 + mg];   \
    f32x4 ar = {GE.r, GE.r, GE.r, GE.r};                                     \
    f32x4 az = {GE.z, GE.z, GE.z, GE.z};                                     \
    f32x4 an = {bn, bn, bn, bn};                                             \
    const float gin = GE.n;                                                  \
    ar = MFMA(a0, wr0, ar); az = MFMA(a0, wz0, az); an = MFMA(a0, wn0, an);  \
    ar = MFMA(a1, wr1, ar); az = MFMA(a1, wz1, az); an = MFMA(a1, wn1, an);  \
    ar = MFMA(a2, wr2, ar); az = MFMA(a2, wz2, az); an = MFMA(a2, wn2, an);  \
    ar = MFMA(a3, wr3, ar); az = MFMA(a3, wz3, az); an = MFMA(a3, wn3, an);  \
    /* gi for step TT+2 (VALU, hides under ds_read/MFMA shadow) */           \
    GE = gdot(XV);                                                           \
    XV = xload((TT) + 4);                                                    \
    /* gates (exp2-prescaled) */                                             \
    float rr = fast_rcp(1.0f + fast_exp2(-ar[0]));                           \
    float zz = fast_rcp(1.0f + fast_exp2(-az[0]));                           \
    float pre = fmaf(rr, an[0], gin);                                        \
    pre = fminf(fmaxf(pre, -40.0f), 40.0f);                                  \
    float e = fast_exp2(-pre);                                               \
    float nn = (1.0f - e) * fast_rcp(1.0f + e);                              \
    hreg = fmaf(zz, hreg - nn, nn);  /* (1-z)*n + z*h */                     \
    if (mg == 0) (WB)[jj] = (half_t)hreg;                                    \
    __syncthreads();                                                         \
  } while (0)

__global__ __launch_bounds__(NTHREADS)
void policy_gru_kernel(const float* __restrict__ particles,
                       const float* __restrict__ weights,
                       const float* __restrict__ Wi, const float* __restrict__ Wh,
                       const float* __restrict__ bh,
                       const float* __restrict__ W1, const float* __restrict__ b1,
                       const float* __restrict__ W2, const float* __restrict__ b2,
                       const float* __restrict__ W3, const float* __restrict__ b3,
                       const float* __restrict__ log_std,
                       float* __restrict__ out)
{
  __shared__ __align__(16) half_t hb[2][H];   // h double buffer
  __shared__ float sg[NTHREADS];
  __shared__ float red[8];

  const int tid = threadIdx.x;
  const int b   = blockIdx.x;
  const int l   = tid & 63;
  const int w   = tid >> 6;      // wave 0..7 owns cols w*16..w*16+15
  const int mg  = l >> 4;        // k-group 0..3
  const int jn  = l & 15;
  const int jj  = w * 16 + jn;   // hidden unit owned by this lane

  const float L1 = 1.4426950408889634f;   // log2(e)
  const float L2 = 2.0f * L1;

  // ---- B-fragments: 3 gates x 4 k-steps over Wh (k<128), prescaled ----
  auto wload = [&](int gate, int s) -> f16x8 {
    f16x8 v;
    const float sc  = (gate == 2) ? L2 : L1;
    const int   col = gate * H + jj;
    #pragma unroll
    for (int r = 0; r < 8; ++r) {
      const int k = s * 32 + mg * 8 + r;
      v[r] = (half_t)(Wh[k * 384 + col] * sc);
    }
    return v;
  };
  const f16x8 wr0 = wload(0,0), wr1 = wload(0,1), wr2 = wload(0,2), wr3 = wload(0,3);
  const f16x8 wz0 = wload(1,0), wz1 = wload(1,1), wz2 = wload(1,2), wz3 = wload(1,3);
  const f16x8 wn0 = wload(2,0), wn1 = wload(2,1), wn2 = wload(2,2), wn3 = wload(2,3);

  // ---- per-lane Wi columns (fp32, prescaled); biases folded into r/z init
  float wir[F], wiz[F], win[F];
  #pragma unroll
  for (int f = 0; f < F; ++f) {
    wir[f] = Wi[f * 384 + jj]       * L1;
    wiz[f] = Wi[f * 384 + 128 + jj] * L1;
    win[f] = Wi[f * 384 + 256 + jj] * L2;
  }
  const float br = bh[jj] * L1, bz = bh[128 + jj] * L1, bn = bh[256 + jj] * L2;

  // ---- uniform x row loader (all lanes same address; tiny traffic) ----
  auto xload = [&](int t) -> XT {
    XT x;
    const int tc = t < T ? t : T - 1;
    const float4* p = (const float4*)(particles + ((size_t)b * T + tc) * D);
    float4 q0 = p[0], q1 = p[1], q2 = p[2], q3 = p[3];
    x.v[0]=q0.x; x.v[1]=q0.y; x.v[2]=q0.z; x.v[3]=q0.w;
    x.v[4]=q1.x; x.v[5]=q1.y; x.v[6]=q1.z; x.v[7]=q1.w;
    x.v[8]=q2.x; x.v[9]=q2.y; x.v[10]=q2.z; x.v[11]=q2.w;
    x.v[12]=q3.x; x.v[13]=q3.y; x.v[14]=q3.z; x.v[15]=q3.w;
    x.v[16] = weights[(size_t)b * T + tc];
    return x;
  };
  auto gdot = [&](const XT& x) -> GI {
    GI g; g.r = br; g.z = bz; g.n = 0.0f;
    #pragma unroll
    for (int f = 0; f < F; ++f) {
      g.r = fmaf(x.v[f], wir[f], g.r);
      g.z = fmaf(x.v[f], wiz[f], g.z);
      g.n = fmaf(x.v[f], win[f], g.n);
    }
    return g;
  };

  // ---- init ----
  if (tid < H) { hb[0][tid] = (half_t)0.f; hb[1][tid] = (half_t)0.f; }
  float hreg = 0.0f;
  GI g_e = gdot(xload(0));
  GI g_o = gdot(xload(1));
  XT xA = xload(2);
  XT xB = xload(3);
  __syncthreads();

  // ---- sequential scan: 1 barrier/step, 12 MFMA/wave/step ----
  for (int t = 0; t < T; t += 2) {
    GSTEP(hb[0], hb[1], g_e, xA, t);
    GSTEP(hb[1], hb[0], g_o, xB, t + 1);
  }

  // ---- MLP head (fp32), one batch per block ----
  if (mg == 0) sg[jj] = hreg;
  __syncthreads();

  float a1 = 0.0f;
  if (tid < 256) {
    a1 = b1[tid];
    #pragma unroll 4
    for (int k = 0; k < H; ++k) a1 = fmaf(sg[k], W1[k * 256 + tid], a1);
    a1 = fmaxf(a1, 0.0f);
    sg[256 + tid] = a1;   // disjoint from sg[0..127]
  }
  __syncthreads();

  float a2 = 0.0f;
  if (tid < 256) {
    a2 = b2[tid];
    #pragma unroll 4
    for (int k = 0; k < 256; ++k) a2 = fmaf(sg[256 + k], W2[k * 256 + tid], a2);
    a2 = fmaxf(a2, 0.0f);
    a2 *= W3[tid];        // W3 is [256,1]
  }
  #pragma unroll
  for (int off = 32; off > 0; off >>= 1) a2 += __shfl_down(a2, off, 64);
  if (tid < 256 && (tid & 63) == 0) red[tid >> 6] = a2;
  __syncthreads();
  if (tid == 0) {
    out[b] = red[0] + red[1] + red[2] + red[3] + b3[0];
    if (b == 0) out[B] = log_std[0];   // second output, flat index 64
  }
}

extern "C" void kernel_launch(void* const* d_in, const int* in_sizes, int n_in,
                              void* d_out, int out_size, void* d_ws, size_t ws_size,
                              hipStream_t stream) {
  const float* particles = (const float*)d_in[0];
  const float* weights   = (const float*)d_in[1];
  const float* Wi      = (const float*)d_in[2];
  const float* Wh      = (const float*)d_in[3];
  const float* bh      = (const float*)d_in[4];
  const float* W1      = (const float*)d_in[5];
  const float* b1      = (const float*)d_in[6];
  const float* W2      = (const float*)d_in[7];
  const float* b2      = (const float*)d_in[8];
  const float* W3      = (const float*)d_in[9];
  const float* b3      = (const float*)d_in[10];
  const float* log_std = (const float*)d_in[11];

  policy_gru_kernel<<<dim3(B), dim3(NTHREADS), 0, stream>>>(
      particles, weights, Wi, Wh, bh, W1, b1, W2, b2, W3, b3, log_std,
      (float*)d_out);
}

// Round 5
// 3039.722 us; speedup vs baseline: 2.0327x; 1.8025x over previous
//
#include <hip/hip_runtime.h>
#include <hip/hip_bf16.h>

#define B 64
#define T 8192
#define D 16
#define H 128
#define F 17        // D + 1 features
#define NTHREADS 512
#define CHUNK 32
#define XSTR 40     // xs row stride in halfs (80 B) — bank-friendly

typedef _Float16 half_t;
typedef _Float16 f16x8 __attribute__((ext_vector_type(8)));
typedef _Float16 f16x4 __attribute__((ext_vector_type(4)));
typedef float f32x4 __attribute__((ext_vector_type(4)));

#define MFMA(a, b, c) __builtin_amdgcn_mfma_f32_16x16x32_f16((a), (b), (c), 0, 0, 0)

__device__ __forceinline__ float fast_rcp(float x) {
#if __has_builtin(__builtin_amdgcn_rcpf)
  return __builtin_amdgcn_rcpf(x);
#else
  return 1.0f / x;
#endif
}
__device__ __forceinline__ float fast_exp2(float x) {
#if __has_builtin(__builtin_amdgcn_exp2f)
  return __builtin_amdgcn_exp2f(x);
#else
  return exp2f(x);
#endif
}

// One GRU step: h from RB (broadcast A-rows), gi from gi_lds, 12 MFMA/wave,
// gates in-lane, h_{t+1} -> WB. One barrier per step.
#define GSTEP(RB, WB, TT)                                                    \
  do {                                                                       \
    const f16x8* hv = (const f16x8*)(RB);                                    \
    f16x8 a0 = hv[mg], a1 = hv[4 + mg], a2 = hv[8 + mg], a3 = hv[12 + mg];   \
    f16x4 gv = *(const f16x4*)(gi_lds + (((TT) & 31) * H + jj) * 4);         \
    const float gr = (float)gv[0], gz = (float)gv[1], gin = (float)gv[2];    \
    f32x4 ar = {gr, gr, gr, gr};                                             \
    f32x4 az = {gz, gz, gz, gz};                                             \
    f32x4 an = {bn, bn, bn, bn};                                             \
    ar = MFMA(a0, wr0, ar); az = MFMA(a0, wz0, az); an = MFMA(a0, wn0, an);  \
    ar = MFMA(a1, wr1, ar); az = MFMA(a1, wz1, az); an = MFMA(a1, wn1, an);  \
    ar = MFMA(a2, wr2, ar); az = MFMA(a2, wz2, az); an = MFMA(a2, wn2, an);  \
    ar = MFMA(a3, wr3, ar); az = MFMA(a3, wz3, az); an = MFMA(a3, wn3, an);  \
    float rr = fast_rcp(1.0f + fast_exp2(-ar[0]));                           \
    float zz = fast_rcp(1.0f + fast_exp2(-az[0]));                           \
    float pre = fmaf(rr, an[0], gin);                                        \
    pre = fminf(fmaxf(pre, -40.0f), 40.0f);                                  \
    float e = fast_exp2(-pre);                                               \
    float nn = (1.0f - e) * fast_rcp(1.0f + e);                              \
    hreg = fmaf(zz, hreg - nn, nn);  /* (1-z)*n + z*h */                     \
    if (mg == 0) (WB)[jj] = (half_t)hreg;                                    \
    __syncthreads();                                                         \
  } while (0)

__global__ __launch_bounds__(NTHREADS, 1)
void policy_gru_kernel(const float* __restrict__ particles,
                       const float* __restrict__ weights,
                       const float* __restrict__ Wi, const float* __restrict__ Wh,
                       const float* __restrict__ bh,
                       const float* __restrict__ W1, const float* __restrict__ b1,
                       const float* __restrict__ W2, const float* __restrict__ b2,
                       const float* __restrict__ W3, const float* __restrict__ b3,
                       const float* __restrict__ log_std,
                       float* __restrict__ out)
{
  __shared__ __align__(16) half_t hb[2][H];               // h double buffer
  __shared__ __align__(16) half_t xs[CHUNK * XSTR];       // staged X chunk (f16)
  __shared__ __align__(16) half_t gi_lds[CHUNK * H * 4];  // gi[tau][j][{r,z,n,pad}]
  __shared__ float sg[NTHREADS];
  __shared__ float red[8];

  const int tid = threadIdx.x;
  const int b   = blockIdx.x;
  const int l   = tid & 63;
  const int w   = tid >> 6;      // wave 0..7 owns cols w*16..w*16+15
  const int mg  = l >> 4;        // k-group 0..3
  const int jn  = l & 15;
  const int jj  = w * 16 + jn;   // hidden unit owned by this lane

  const float L1 = 1.4426950408889634f;   // log2(e)
  const float L2 = 2.0f * L1;

  // ---- Wh B-fragments: 3 gates x 4 k-steps (prescaled for exp2 gates) ----
  auto wload = [&](int gate, int s) -> f16x8 {
    f16x8 v;
    const float sc  = (gate == 2) ? L2 : L1;
    const int   col = gate * H + jj;
    #pragma unroll
    for (int r = 0; r < 8; ++r) {
      const int k = s * 32 + mg * 8 + r;
      v[r] = (half_t)(Wh[k * 384 + col] * sc);
    }
    return v;
  };
  const f16x8 wr0 = wload(0,0), wr1 = wload(0,1), wr2 = wload(0,2), wr3 = wload(0,3);
  const f16x8 wz0 = wload(1,0), wz1 = wload(1,1), wz2 = wload(1,2), wz3 = wload(1,3);
  const f16x8 wn0 = wload(2,0), wn1 = wload(2,1), wn2 = wload(2,2), wn3 = wload(2,3);

  // ---- Wi B-fragments (same columns as Wh frags), K padded 17->32 ----
  auto wiload = [&](int gate) -> f16x8 {
    f16x8 v;
    const float sc  = (gate == 2) ? L2 : L1;
    const int   col = gate * H + jj;
    #pragma unroll
    for (int i = 0; i < 8; ++i) {
      const int k = mg * 8 + i;
      v[i] = (half_t)(k < F ? Wi[k * 384 + col] * sc : 0.0f);
    }
    return v;
  };
  const f16x8 wiR = wiload(0), wiZ = wiload(1), wiN = wiload(2);
  const float br = bh[jj] * L1, bz = bh[128 + jj] * L1, bn = bh[256 + jj] * L2;

  // ---- X chunk prefetch: 544 elements over 512 threads (<=2 each) ----
  const int e0 = tid, e1 = tid + NTHREADS;
  float xr0 = 0.f, xr1 = 0.f;
  auto xfetch = [&](int t0) {
    auto ld = [&](int e) -> float {
      const int tau = e / F, f = e % F;
      int t = t0 + tau; if (t > T - 1) t = T - 1;
      return (f < D) ? particles[((size_t)b * T + t) * D + f]
                     : weights[(size_t)b * T + t];
    };
    xr0 = ld(e0);
    if (e1 < CHUNK * F) xr1 = ld(e1);
  };
  auto xstage = [&]() {
    xs[(e0 / F) * XSTR + (e0 % F)] = (half_t)xr0;
    if (e1 < CHUNK * F) xs[(e1 / F) * XSTR + (e1 % F)] = (half_t)xr1;
  };

  // ---- chunk gi matmul: X[32x17] @ Wi -> gi_lds (6 MFMA/wave) ----
  auto gi_compute = [&]() {
    f16x8 aX0 = *(const f16x8*)(xs + (jn     ) * XSTR + mg * 8);
    f16x8 aX1 = *(const f16x8*)(xs + (jn + 16) * XSTR + mg * 8);
    f32x4 cr0 = {br, br, br, br}, cz0 = {bz, bz, bz, bz}, cn0 = {0.f,0.f,0.f,0.f};
    f32x4 cr1 = cr0, cz1 = cz0, cn1 = cn0;
    cr0 = MFMA(aX0, wiR, cr0); cz0 = MFMA(aX0, wiZ, cz0); cn0 = MFMA(aX0, wiN, cn0);
    cr1 = MFMA(aX1, wiR, cr1); cz1 = MFMA(aX1, wiZ, cz1); cn1 = MFMA(aX1, wiN, cn1);
    #pragma unroll
    for (int r = 0; r < 4; ++r) {
      const int t0r = (l >> 4) * 4 + r;       // D row = timestep within chunk
      gi_lds[(t0r * H + jj) * 4 + 0] = (half_t)cr0[r];
      gi_lds[(t0r * H + jj) * 4 + 1] = (half_t)cz0[r];
      gi_lds[(t0r * H + jj) * 4 + 2] = (half_t)cn0[r];
      const int t1r = t0r + 16;
      gi_lds[(t1r * H + jj) * 4 + 0] = (half_t)cr1[r];
      gi_lds[(t1r * H + jj) * 4 + 1] = (half_t)cz1[r];
      gi_lds[(t1r * H + jj) * 4 + 2] = (half_t)cn1[r];
    }
  };

  // ---- init ----
  float hreg = 0.0f;
  if (tid < H) { hb[0][tid] = (half_t)0.f; hb[1][tid] = (half_t)0.f; }
  for (int i = tid; i < CHUNK * XSTR; i += NTHREADS) xs[i] = (half_t)0.f;
  xfetch(0);
  __syncthreads();          // zeros visible before staging
  xstage();
  xfetch(CHUNK);            // prefetch next chunk
  __syncthreads();          // xs visible
  gi_compute();
  __syncthreads();          // gi visible

  // ---- sequential scan: 1 barrier/step, 12 MFMA/wave/step ----
  for (int t0 = 0; t0 < T; t0 += CHUNK) {
    #pragma unroll 4
    for (int tt = 0; tt < CHUNK; tt += 2) {
      GSTEP(hb[0], hb[1], tt);
      GSTEP(hb[1], hb[0], tt + 1);
    }
    if (t0 + CHUNK < T) {
      xstage();                    // stage chunk t0+32 (regs loaded last time)
      xfetch(t0 + 2 * CHUNK);      // prefetch chunk t0+64 (clamped)
      __syncthreads();             // xs visible
      gi_compute();
      __syncthreads();             // gi visible
    }
  }

  // ---- MLP head (fp32), one batch per block ----
  if (mg == 0) sg[jj] = hreg;
  __syncthreads();

  float a1 = 0.0f;
  if (tid < 256) {
    a1 = b1[tid];
    #pragma unroll 4
    for (int k = 0; k < H; ++k) a1 = fmaf(sg[k], W1[k * 256 + tid], a1);
    a1 = fmaxf(a1, 0.0f);
    sg[256 + tid] = a1;   // disjoint from sg[0..127]
  }
  __syncthreads();

  float a2 = 0.0f;
  if (tid < 256) {
    a2 = b2[tid];
    #pragma unroll 4
    for (int k = 0; k < 256; ++k) a2 = fmaf(sg[256 + k], W2[k * 256 + tid], a2);
    a2 = fmaxf(a2, 0.0f);
    a2 *= W3[tid];        // W3 is [256,1]
  }
  #pragma unroll
  for (int off = 32; off > 0; off >>= 1) a2 += __shfl_down(a2, off, 64);
  if (tid < 256 && (tid & 63) == 0) red[tid >> 6] = a2;
  __syncthreads();
  if (tid == 0) {
    out[b] = red[0] + red[1] + red[2] + red[3] + b3[0];
    if (b == 0) out[B] = log_std[0];   // second output, flat index 64
  }
}

extern "C" void kernel_launch(void* const* d_in, const int* in_sizes, int n_in,
                              void* d_out, int out_size, void* d_ws, size_t ws_size,
                              hipStream_t stream) {
  const float* particles = (const float*)d_in[0];
  const float* weights   = (const float*)d_in[1];
  const float* Wi      = (const float*)d_in[2];
  const float* Wh      = (const float*)d_in[3];
  const float* bh      = (const float*)d_in[4];
  const float* W1      = (const float*)d_in[5];
  const float* b1      = (const float*)d_in[6];
  const float* W2      = (const float*)d_in[7];
  const float* b2      = (const float*)d_in[8];
  const float* W3      = (const float*)d_in[9];
  const float* b3      = (const float*)d_in[10];
  const float* log_std = (const float*)d_in[11];

  policy_gru_kernel<<<dim3(B), dim3(NTHREADS), 0, stream>>>(
      particles, weights, Wi, Wh, bh, W1, b1, W2, b2, W3, b3, log_std,
      (float*)d_out);
}